// Round 6
// baseline (4325.262 us; speedup 1.0000x reference)
//
#include <hip/hip_runtime.h>
#include <stdint.h>

// SequenceDecoder: B=128, EMB=512, H=1024, V=8192, T=100 (99 sequential steps).
//  - argmax(log_softmax) == argmax(raw): recurrence needs only raw-logit argmax.
//  - fp16 hi/lo split GEMMs (3 MFMA passes, lo x2048) ~22 mantissa bits.
//  - Weights pre-converted ONCE to fp16 hi|lo tile images, LDS XOR-swizzle
//    (chunk ^= row&7) baked in. K-loop staging = global_load_lds 16B DMA.
//  - gi table: gi = emb @ w_ih.T + b_ih for all 8192 vocab rows precomputed;
//    gates GEMM is h-part only (K=1024), GRU fused in epilogue.
//  - PERSISTENT kernel (256 WGs x 256 thr, 80KB LDS -> 1 WG/CU co-resident),
//    RELAXED-atomic grid barriers (no per-step cache maintenance).
//  - r6 change: hpre = 100-deep ring (one buffer per step). Addresses are
//    write-once/read-once within a launch -> readers use NORMAL CACHED DMA
//    (r5's sc0sc1 bypass forced ~72 MB/step through the LLC = the dominant
//    cost). Writers stay write-through (st16sc, no dirty L2 lines). Cross-
//    launch staleness handled by ONE agent-scope acquire (L2 inv) at entry.

#define Bb   128
#define EMBd 512
#define Hd   1024
#define Vd   8192
#define Td   100
#define HPB  524288   // hpre bytes per step buffer (32 st * 128 b * 128 B)

typedef __attribute__((ext_vector_type(8))) _Float16 half8;
typedef __attribute__((ext_vector_type(4))) float f32x4;
typedef unsigned long long ull;

#define LOSCALE 2048.0f
#define LOINV   (1.0f/2048.0f)

#define WAITV(N) do { asm volatile("s_waitcnt vmcnt(" #N ")" ::: "memory"); \
                      __builtin_amdgcn_sched_barrier(0); } while (0)
#define WAITL    do { asm volatile("s_waitcnt lgkmcnt(0)" ::: "memory");    \
                      __builtin_amdgcn_sched_barrier(0); } while (0)

__device__ __forceinline__ uint32_t fkey(float f) {
  uint32_t u = __float_as_uint(f);
  return (u & 0x80000000u) ? ~u : (u | 0x80000000u);
}
__device__ __forceinline__ ull umax64(ull a, ull b) { return a > b ? a : b; }

__device__ __forceinline__ void dma16(const void* g, void* l) {
  __builtin_amdgcn_global_load_lds((const uint32_t*)g, (uint32_t*)l, 16, 0, 0);
}
// write-through 16B store (no dirty L2 line; visible at LLC once vmcnt retires)
__device__ __forceinline__ void st16sc(void* p, half8 v) {
  f32x4 d = *(f32x4*)&v;
  asm volatile("global_store_dwordx4 %0, %1, off sc0 sc1"
               :: "v"(p), "v"(d) : "memory");
}
__device__ __forceinline__ ull sysld64(const ull* p) {
  return __hip_atomic_load((ull*)p, __ATOMIC_RELAXED, __HIP_MEMORY_SCOPE_SYSTEM);
}

// split 8 fp32 into fp16 hi + (lo*2048)
__device__ __forceinline__ void cvt8(const float4 v0, const float4 v1,
                                     half8& hh, half8& ll) {
  float vv[8] = {v0.x, v0.y, v0.z, v0.w, v1.x, v1.y, v1.z, v1.w};
#pragma unroll
  for (int i = 0; i < 8; ++i) {
    _Float16 h = (_Float16)vv[i];
    hh[i] = h;
    ll[i] = (_Float16)((vv[i] - (float)h) * LOSCALE);
  }
}

// ---------------------------------------------------------------- init
__global__ void k_init(const float* __restrict__ x, float* __restrict__ hbuf0,
                       ull* __restrict__ amax, char* __restrict__ hpre0,
                       uint32_t* __restrict__ bar) {
  int tid = blockIdx.x * 256 + threadIdx.x;
  if (tid < Bb * Hd) hbuf0[tid] = x[tid];
  if (tid < Td * Bb) amax[tid] = (tid < Bb) ? 0xFFFFFFFFull : 0ull;  // t=0: idx=0
  if (tid >= 16384 && tid < 16384 + 256) bar[tid - 16384] = 0;
  if (tid < 16384) {
    int b = tid & 127, sc = tid >> 7;
    int st = sc >> 2, c = sc & 3;
    const float* src = x + b * Hd + st * 32 + c * 8;
    float4 v0 = *(const float4*)src, v1 = *(const float4*)(src + 4);
    half8 hh, ll; cvt8(v0, v1, hh, ll);
    char* hp = hpre0 + st * 16384 + b * 128;
    *(half8*)(hp + ((c       ^ (b & 7))) * 16) = hh;
    *(half8*)(hp + (((c + 4) ^ (b & 7))) * 16) = ll;
  }
}

// ------------------------------------------------------------- prep kernels
// emb_pre: [row 8192][st_e 16][chunk 8][16B], UNSWIZZLED
__global__ void k_prep_emb(const float* __restrict__ emb, char* __restrict__ embp) {
  int t = blockIdx.x * 256 + threadIdx.x;          // 524288 total
  int row = t >> 6, rem = t & 63, st = rem >> 2, c = rem & 3;
  const float* src = emb + (size_t)row * EMBd + st * 32 + c * 8;
  float4 v0 = *(const float4*)src, v1 = *(const float4*)(src + 4);
  half8 hh, ll; cvt8(v0, v1, hh, ll);
  char* d = embp + (size_t)row * 2048 + st * 128;
  *(half8*)(d + c * 16) = hh;
  *(half8*)(d + (c + 4) * 16) = ll;
}

// wpre: per (cg,q,st) tile: [48 rows][128B], swizzled (chunk ^= r&7)
__global__ void k_prep_w(const float* __restrict__ w_ih, const float* __restrict__ w_hh,
                         char* __restrict__ wpre) {
  int bi = blockIdx.x;                 // (cg*4+q)*12+st, 3072 blocks
  int st = bi % 12, t2 = bi / 12, q = t2 & 3, cg = t2 >> 2;
  int t = threadIdx.x; if (t >= 192) return;
  int r = t >> 2, c = t & 3;
  int g = r >> 4, bn = r & 15;
  int k0 = q * 384 + st * 32 + c * 8;
  const float* src = (k0 < 512)
    ? (w_ih + (size_t)(g * 1024 + cg * 16 + bn) * EMBd + k0)
    : (w_hh + (size_t)(g * 1024 + cg * 16 + bn) * Hd + (k0 - 512));
  float4 v0 = *(const float4*)src, v1 = *(const float4*)(src + 4);
  half8 hh, ll; cvt8(v0, v1, hh, ll);
  char* d = wpre + (size_t)bi * 6144 + r * 128;
  *(half8*)(d + ((c       ^ (r & 7))) * 16) = hh;
  *(half8*)(d + (((c + 4) ^ (r & 7))) * 16) = ll;
}

// clspre: [ct 128][st 32][64 rows][128B], swizzled
__global__ void k_prep_cls(const float* __restrict__ cls_w, char* __restrict__ clsp) {
  int b = blockIdx.x;                  // ct*32+st, 4096 blocks
  int ct = b >> 5, st = b & 31;
  int t = threadIdx.x;
  int r = t >> 2, c = t & 3;
  const float* src = cls_w + (size_t)(ct * 64 + r) * Hd + st * 32 + c * 8;
  float4 v0 = *(const float4*)src, v1 = *(const float4*)(src + 4);
  half8 hh, ll; cvt8(v0, v1, hh, ll);
  char* d = clsp + (size_t)b * 8192 + r * 128;
  *(half8*)(d + ((c       ^ (r & 7))) * 16) = hh;
  *(half8*)(d + (((c + 4) ^ (r & 7))) * 16) = ll;
}

// ------------------------------------------- gi table: emb @ w_ih.T + b_ih
__global__ __launch_bounds__(256, 2) void k_prep_gi(
    const char* __restrict__ embp, const char* __restrict__ wpre,
    const float* __restrict__ b_ih, float* __restrict__ gi)
{
  const int cg = blockIdx.x, vh = blockIdx.y;
  const int tid = threadIdx.x, lane = tid & 63, w = tid >> 6;
  const int C = cg * 16;
  __shared__ __align__(16) char pA[4 * 8192];
  __shared__ __align__(16) char pB[4 * 6144];

  f32x4 accH[3], accL[3];
#pragma unroll
  for (int g = 0; g < 3; ++g) {
    accH[g] = (f32x4){0.f, 0.f, 0.f, 0.f};
    accL[g] = (f32x4){0.f, 0.f, 0.f, 0.f};
  }

  const int rr = lane >> 3, cc = lane & 7;
  const char* abase = embp + (size_t)(vh * 64 + w * 16 + rr) * 2048 + ((cc ^ rr) * 16);

  auto issue = [&](int st) {
    char* da = pA + (st & 3) * 8192 + w * 2048;
    const char* s0 = abase + st * 128;
    dma16(s0, da);
    dma16(s0 + 8 * 2048, da + 1024);
    const int wq = st / 12, wst = st - wq * 12;
    const char* sb = wpre + (size_t)((cg * 4 + wq) * 12 + wst) * 6144 + w * 1536 + lane * 16;
    char* db = pB + (st & 3) * 6144 + w * 1536;
    dma16(sb, db);
    if (lane < 32) dma16(sb + 1024, db + 1024);
  };

  const int l15 = lane & 15, qd = lane >> 4, r7 = l15 & 7;
  const int offAH = (w * 16 + l15) * 128 + ((qd)     ^ r7) * 16;
  const int offAL = (w * 16 + l15) * 128 + ((qd + 4) ^ r7) * 16;

  issue(0); issue(1); issue(2);
  WAITV(8);
  __builtin_amdgcn_s_barrier();

  for (int st = 0; st < 16; ++st) {
    const int bf = st & 3;
    half8 aH = *(half8*)&pA[bf * 8192 + offAH];
    half8 aL = *(half8*)&pA[bf * 8192 + offAL];
    if (st + 3 < 16) issue(st + 3);
#pragma unroll
    for (int g = 0; g < 3; ++g) {
      half8 bH = *(half8*)&pB[bf * 6144 + (g * 16 + l15) * 128 + ((qd)     ^ r7) * 16];
      half8 bL = *(half8*)&pB[bf * 6144 + (g * 16 + l15) * 128 + ((qd + 4) ^ r7) * 16];
      accH[g] = __builtin_amdgcn_mfma_f32_16x16x32_f16(aH, bH, accH[g], 0, 0, 0);
      accL[g] = __builtin_amdgcn_mfma_f32_16x16x32_f16(aH, bL, accL[g], 0, 0, 0);
      accL[g] = __builtin_amdgcn_mfma_f32_16x16x32_f16(aL, bH, accL[g], 0, 0, 0);
    }
    if (st < 15) {
      if (st <= 12)      { WAITV(8); }
      else if (st == 13) { WAITV(4); }
      else               { WAITV(0); }
      WAITL;
      __builtin_amdgcn_s_barrier();
    }
  }

  const int v0 = vh * 64 + w * 16 + qd * 4;
#pragma unroll
  for (int g = 0; g < 3; ++g) {
    float bi = b_ih[g * 1024 + C + l15];
#pragma unroll
    for (int i = 0; i < 4; ++i) {
      float val = accH[g][i] + accL[g][i] * LOINV + bi;
      gi[(size_t)(v0 + i) * 3072 + g * 1024 + C + l15] = val;
    }
  }
}

// ---------------------------------------------------------- grid barrier
// RELAXED two-level barrier: 8 group counters -> root. NO acq/rel (no cache
// maintenance). Ordering: __syncthreads drains vmcnt (sc-stores visible)
// before tid0 signals; within a launch every hpre buffer is write-once/
// read-once, so cached reads can never be stale.
__device__ __forceinline__ void relbar(uint32_t* __restrict__ bar, int wg, uint32_t gen) {
  __syncthreads();
  if (threadIdx.x == 0) {
    const int g = wg & 7;
    uint32_t old = __hip_atomic_fetch_add(&bar[g * 16], 1u, __ATOMIC_RELAXED,
                                          __HIP_MEMORY_SCOPE_SYSTEM);
    if (old + 1u == gen * 32u)
      __hip_atomic_fetch_add(&bar[128], 1u, __ATOMIC_RELAXED,
                             __HIP_MEMORY_SCOPE_SYSTEM);
    while (__hip_atomic_load(&bar[128], __ATOMIC_RELAXED,
                             __HIP_MEMORY_SCOPE_SYSTEM) < gen * 8u)
      __builtin_amdgcn_s_sleep(4);
  }
  __syncthreads();
}

// ----------------------------------------------- persistent full-loop kernel
__global__ __launch_bounds__(256) void k_loop(
    const char* __restrict__ wpre, const char* __restrict__ clsp,
    const float* __restrict__ gi,
    const float* __restrict__ b_hh, const float* __restrict__ cls_b,
    float* __restrict__ hbuf, char* __restrict__ hpre,
    ull* __restrict__ amax, float* __restrict__ out,
    uint32_t* __restrict__ bar)
{
  const int wg = blockIdx.x;
  const int tid = threadIdx.x, lane = tid & 63, w = tid >> 6;
  __shared__ __align__(16) char smem[81920];   // 80KB -> 1 WG/CU guaranteed

  // ---- once per LAUNCH: agent-scope acquire -> L1+L2 invalidate. Kills any
  // stale lines cached during a previous graph replay (hpre ring addresses
  // are reused across launches). relbar stays relaxed (no per-step inv).
  if (tid == 0)
    (void)__hip_atomic_load(&bar[160], __ATOMIC_ACQUIRE, __HIP_MEMORY_SCOPE_AGENT);
  __syncthreads();

  const int l15 = lane & 15, qd = lane >> 4, r7 = l15 & 7;

  // gates role (wg < 128): cg = wg&63, rh = bit6
  const int cg = wg & 63, rh = (wg >> 6) & 1;
  const int C = cg * 16;
  // cls role (all): ct = wg&127, rt0 = bit7
  const int ct = wg & 127, rt0 = wg >> 7;
  const int r0c = rt0 * 64, c0c = ct * 64;
  const char* c_bsrc = clsp + (size_t)ct * 262144 + w * 2048 + lane * 16;

  const int offA_H = (w * 16 + l15) * 128 + ((qd)     ^ r7) * 16;
  const int offA_L = (w * 16 + l15) * 128 + ((qd + 4) ^ r7) * 16;

  uint32_t gen = 0;

  for (int s = 1; s < Td; ++s) {
    const int pPrev = (s - 1) & 1, pCur = s & 1;
    const char* hpre_rd = hpre + (size_t)(s - 1) * HPB;   // written at step s-1
    char*       hpre_wr = hpre + (size_t)s * HPB;         // fresh this step

    // ================== gates GEMM (h-part, K=1024) + fused GRU ==========
    if (wg < 128) {
      const ull* amax_prev = amax + (size_t)(s - 1) * Bb;
      const char* hsrc = hpre_rd + rh * 8192 + w * 2048 + lane * 16;  // +st*16384
      char* gA = smem;               // 4 * 8192
      char* gB = smem + 32768;       // 4 * 6144

      f32x4 accH[3], accL[3];
#pragma unroll
      for (int g = 0; g < 3; ++g) {
        accH[g] = (f32x4){0.f, 0.f, 0.f, 0.f};
        accL[g] = (f32x4){0.f, 0.f, 0.f, 0.f};
      }

      auto issue = [&](int st) {
        char* da = gA + (st & 3) * 8192 + w * 2048;
        const char* sa = hsrc + st * 16384;
        dma16(sa, da);                     // hpre: cached (write-once ring)
        dma16(sa + 1024, da + 1024);
        const int k0 = 512 + st * 32;
        const int wq = (k0 >= 1152) ? 3 : (k0 >= 768 ? 2 : 1);
        const int wst = (k0 - wq * 384) >> 5;
        const char* sb = wpre + (size_t)((cg * 4 + wq) * 12 + wst) * 6144 + w * 1536 + lane * 16;
        char* db = gB + (st & 3) * 6144 + w * 1536;
        dma16(sb, db);                     // weights: cached
        if (lane < 32) dma16(sb + 1024, db + 1024);
      };

      issue(0); issue(1); issue(2);
      WAITV(8);
      __builtin_amdgcn_s_barrier();

      for (int st = 0; st < 32; ++st) {
        const int bf = st & 3;
        half8 aH = *(half8*)&gA[bf * 8192 + offA_H];
        half8 aL = *(half8*)&gA[bf * 8192 + offA_L];
        if (st + 3 < 32) issue(st + 3);
#pragma unroll
        for (int g = 0; g < 3; ++g) {
          half8 bH = *(half8*)&gB[bf * 6144 + (g * 16 + l15) * 128 + ((qd)     ^ r7) * 16];
          half8 bL = *(half8*)&gB[bf * 6144 + (g * 16 + l15) * 128 + ((qd + 4) ^ r7) * 16];
          accH[g] = __builtin_amdgcn_mfma_f32_16x16x32_f16(aH, bH, accH[g], 0, 0, 0);
          accL[g] = __builtin_amdgcn_mfma_f32_16x16x32_f16(aH, bL, accL[g], 0, 0, 0);
          accL[g] = __builtin_amdgcn_mfma_f32_16x16x32_f16(aL, bH, accL[g], 0, 0, 0);
        }
        if (st < 31) {
          if (st <= 28)      { WAITV(8); }
          else if (st == 29) { WAITV(4); }
          else               { WAITV(0); }
          WAITL;
          __builtin_amdgcn_s_barrier();
        }
      }

      // GRU epilogue: 4 rows x 1 col per lane
      const int j = C + l15;
      const float bh0 = b_hh[j], bh1 = b_hh[1024 + j], bh2 = b_hh[2048 + j];
      const float* hprev_f = hbuf + (size_t)pPrev * Bb * Hd;
      float* hnew_f = hbuf + (size_t)pCur * Bb * Hd;
      float outs[4];
#pragma unroll
      for (int i = 0; i < 4; ++i) {
        const int ri = rh * 64 + w * 16 + qd * 4 + i;
        const uint32_t idx = (~(uint32_t)sysld64(&amax_prev[ri])) & 8191u;
        const float* gp = gi + (size_t)idx * 3072 + j;
        float i_r = gp[0], i_z = gp[1024], i_n = gp[2048];
        float h_r = accH[0][i] + accL[0][i] * LOINV + bh0;
        float h_z = accH[1][i] + accL[1][i] * LOINV + bh1;
        float h_n = accH[2][i] + accL[2][i] * LOINV + bh2;
        float rr2 = 1.f / (1.f + expf(-(i_r + h_r)));
        float zz = 1.f / (1.f + expf(-(i_z + h_z)));
        float nn = tanhf(i_n + rr2 * h_n);
        float o = (1.f - zz) * nn + zz * hprev_f[ri * Hd + j];
        hnew_f[ri * Hd + j] = o;          // WG-private slice (persistent WG)
        outs[i] = o;
      }
      // transpose via LDS -> 16B write-through hpre stores
      __syncthreads();
      float* sT = (float*)smem;
#pragma unroll
      for (int i = 0; i < 4; ++i)
        sT[(w * 16 + qd * 4 + i) * 16 + l15] = outs[i];
      __syncthreads();
      if (tid < 128) {
        const int row = tid >> 1, half = tid & 1;
        const int b = rh * 64 + row;
        const float* srcp = sT + row * 16 + half * 8;
        half8 hh, ll;
#pragma unroll
        for (int e = 0; e < 8; ++e) {
          float o = srcp[e];
          _Float16 oh = (_Float16)o;
          hh[e] = oh;
          ll[e] = (_Float16)((o - (float)oh) * LOSCALE);
        }
        const int stp = C >> 5;
        const int chb = ((C & 31) >> 3) + half;
        char* hp = hpre_wr + stp * 16384 + b * 128;
        st16sc(hp + ((chb       ^ (b & 7))) * 16, hh);
        st16sc(hp + (((chb + 4) ^ (b & 7))) * 16, ll);
      }
    }

    ++gen; relbar(bar, wg, gen);   // h tiles (sc-written) visible

    // ======================= cls GEMM + argmax =======================
    {
      const char* asrc = hpre_wr + rt0 * 8192 + w * 2048 + lane * 16;  // +st*16384
      char* cA = smem;               // 4 * 8192
      char* cB = smem + 32768;       // 4 * 8192

      f32x4 accH[4], accL[4];
#pragma unroll
      for (int i = 0; i < 4; ++i) {
        accH[i] = (f32x4){0.f, 0.f, 0.f, 0.f};
        accL[i] = (f32x4){0.f, 0.f, 0.f, 0.f};
      }

      auto issue = [&](int st) {
        char* da = cA + (st & 3) * 8192 + w * 2048;
        const char* sa = asrc + st * 16384;
        dma16(sa, da);                     // hpre: cached (fresh buffer)
        dma16(sa + 1024, da + 1024);
        char* db = cB + (st & 3) * 8192 + w * 2048;
        const char* sb = c_bsrc + st * 8192;
        dma16(sb, db);                     // weights: cached
        dma16(sb + 1024, db + 1024);
      };

      issue(0); issue(1); issue(2);
      WAITV(8);
      __builtin_amdgcn_s_barrier();

      for (int st = 0; st < 32; ++st) {
        const int bf = st & 3;
        half8 aH = *(half8*)&cA[bf * 8192 + offA_H];
        half8 aL = *(half8*)&cA[bf * 8192 + offA_L];
        if (st + 3 < 32) issue(st + 3);
#pragma unroll
        for (int cf = 0; cf < 4; ++cf) {
          half8 bH = *(half8*)&cB[bf * 8192 + (cf * 16 + l15) * 128 + ((qd)     ^ r7) * 16];
          half8 bL = *(half8*)&cB[bf * 8192 + (cf * 16 + l15) * 128 + ((qd + 4) ^ r7) * 16];
          accH[cf] = __builtin_amdgcn_mfma_f32_16x16x32_f16(aH, bH, accH[cf], 0, 0, 0);
          accL[cf] = __builtin_amdgcn_mfma_f32_16x16x32_f16(aH, bL, accL[cf], 0, 0, 0);
          accL[cf] = __builtin_amdgcn_mfma_f32_16x16x32_f16(aL, bH, accL[cf], 0, 0, 0);
        }
        if (st < 31) {
          if (st <= 28)      { WAITV(8); }
          else if (st == 29) { WAITV(4); }
          else               { WAITV(0); }
          WAITL;
          __builtin_amdgcn_s_barrier();
        }
      }

      // epilogue: +bias, nontemporal logit stores, packed argmax atomicMax
      float bsv[4];
#pragma unroll
      for (int cf = 0; cf < 4; ++cf) bsv[cf] = cls_b[c0c + cf * 16 + l15];
#pragma unroll
      for (int i = 0; i < 4; ++i) {
        const int brow = r0c + w * 16 + qd * 4 + i;
        float* orow = out + ((size_t)brow * Td + s) * Vd;
        ull best = 0ull;
#pragma unroll
        for (int cf = 0; cf < 4; ++cf) {
          const int v = c0c + cf * 16 + l15;
          float val = accH[cf][i] + accL[cf][i] * LOINV + bsv[cf];
          __builtin_nontemporal_store(val, &orow[v]);
          best = umax64(best, ((ull)fkey(val) << 32) | (uint32_t)(~(uint32_t)v));
        }
        best = umax64(best, __shfl_xor(best, 1));
        best = umax64(best, __shfl_xor(best, 2));
        best = umax64(best, __shfl_xor(best, 4));
        best = umax64(best, __shfl_xor(best, 8));
        if (l15 == 0) atomicMax(&amax[(size_t)s * Bb + brow], best);
      }
    }

    ++gen; relbar(bar, wg, gen);   // amax done for next step's gather
  }
}

// -------------------------------------------------- final log_softmax pass
__global__ void k_softmax(float* __restrict__ out,
                          const ull* __restrict__ amax) {
  int blk = blockIdx.x;           // 12800 = 128*100
  int t = blk % Td, b = blk / Td;
  int tid = threadIdx.x;
  float* row = out + ((size_t)b * Td + t) * Vd;
  if (t == 0) {
    float lse0 = logf(expf(1.0f) + (float)(Vd - 1));
    for (int i = tid; i < Vd; i += 256) row[i] = ((i == 0) ? 1.0f : 0.0f) - lse0;
    return;
  }
  ull key = amax[t * Bb + b];
  uint32_t ku = (uint32_t)(key >> 32);
  uint32_t u = (ku & 0x80000000u) ? (ku & 0x7fffffffu) : ~ku;
  float m = __uint_as_float(u);
  float x[32];
  float ssum = 0.f;
#pragma unroll
  for (int i = 0; i < 32; ++i) {
    x[i] = row[tid + i * 256];
    ssum += expf(x[i] - m);
  }
  ssum += __shfl_xor(ssum, 1);
  ssum += __shfl_xor(ssum, 2);
  ssum += __shfl_xor(ssum, 4);
  ssum += __shfl_xor(ssum, 8);
  ssum += __shfl_xor(ssum, 16);
  ssum += __shfl_xor(ssum, 32);
  __shared__ float wsum[4];
  if ((tid & 63) == 0) wsum[tid >> 6] = ssum;
  __syncthreads();
  float lse = m + logf(wsum[0] + wsum[1] + wsum[2] + wsum[3]);
#pragma unroll
  for (int i = 0; i < 32; ++i) row[tid + i * 256] = x[i] - lse;
}

// ----------------------------------------------------------------- launch
extern "C" void kernel_launch(void* const* d_in, const int* in_sizes, int n_in,
                              void* d_out, int out_size, void* d_ws, size_t ws_size,
                              hipStream_t stream) {
  const float* x     = (const float*)d_in[0];
  const float* emb   = (const float*)d_in[1];
  const float* w_ih  = (const float*)d_in[2];
  const float* w_hh  = (const float*)d_in[3];
  const float* b_ih  = (const float*)d_in[4];
  const float* b_hh  = (const float*)d_in[5];
  const float* cls_w = (const float*)d_in[6];
  const float* cls_b = (const float*)d_in[7];
  float* out = (float*)d_out;

  char* ws = (char*)d_ws;
  size_t o = 0;
  ull*      amax = (ull*)(ws + o);      o += (size_t)Td * Bb * 8;      // 100 KB
  uint32_t* bar  = (uint32_t*)(ws + o); o += 1024;
  float*    hbuf = (float*)(ws + o);    o += (size_t)2 * Bb * Hd * 4;  // 1 MB
  char*     hpre = ws + o;              o += (size_t)Td * HPB;         // 52.4 MB
  char*     embp = ws + o;              o += (size_t)Vd * 2048;        // 16.8 MB
  char*     wpre = ws + o;              o += (size_t)3072 * 6144;      // 18.9 MB
  char*     clsp = ws + o;              o += (size_t)128 * 32 * 8192;  // 33.6 MB
  float*    gi   = (float*)(ws + o);    o += (size_t)Vd * 3072 * 4;    // 100.7 MB

  k_init<<<512, 256, 0, stream>>>(x, hbuf, amax, hpre, bar);
  k_prep_emb<<<2048, 256, 0, stream>>>(emb, embp);
  k_prep_w<<<3072, 256, 0, stream>>>(w_ih, w_hh, wpre);
  k_prep_cls<<<4096, 256, 0, stream>>>(cls_w, clsp);
  k_prep_gi<<<dim3(64, 128), 256, 0, stream>>>(embp, wpre, b_ih, gi);

  k_loop<<<256, 256, 0, stream>>>(wpre, clsp, gi, b_hh, cls_b,
                                  hbuf, hpre, amax, out, bar);

  k_softmax<<<12800, 256, 0, stream>>>(out, amax);
}